// Round 1
// baseline (473.309 us; speedup 1.0000x reference)
//
#include <hip/hip_runtime.h>
#include <stdint.h>

#define TILES 8
#define HH 4096
#define WW 4096
#define CC 3
#define TH 512
#define TW 512
#define AREA (TH * TW)
#define CLIPV 1228u   // int(1.2 * 262144 / 256)

// ---------------------------------------------------------------------------
// Pass 1: per-tile histograms + cache quantized v bytes.
// grid = C*64 tiles * 8 sub-blocks = 1536 blocks, 256 threads.
// Each block: 64 rows x 512 cols of one tile, float4 loads.
// ---------------------------------------------------------------------------
__global__ __launch_bounds__(256) void clahe_hist_kernel(
    const float* __restrict__ img,
    uint32_t* __restrict__ vpack,   // packed v bytes (4 per uint), may be unused
    int store_v,
    uint32_t* __restrict__ hist)    // [C*64][256]
{
    __shared__ uint32_t sh[4 * 264];   // 4 per-wave sub-hists, staggered by 8
    const int tid  = threadIdx.x;
    const int wave = tid >> 6;
    uint32_t* myh  = sh + wave * 264;

    for (int i = tid; i < 4 * 264; i += 256) sh[i] = 0;
    __syncthreads();

    const int bid = blockIdx.x;
    const int sub = bid & 7;        // which 64-row slab of the tile
    const int tl  = bid >> 3;       // c*64 + ty*8 + tx
    const int tx  = tl & 7;
    const int ty  = (tl >> 3) & 7;
    const int c   = tl >> 6;

    const size_t base = ((size_t)c * HH + (size_t)(ty * TH + sub * 64)) * WW + (size_t)tx * TW;

#pragma unroll 4
    for (int it = 0; it < 32; ++it) {
        const int i  = it * 256 + tid;      // [0, 8192) float4 slots
        const int rl = i >> 7;              // 128 float4 per 512-wide row
        const int c4 = i & 127;
        const size_t addr = base + (size_t)rl * WW + (size_t)c4 * 4;  // element idx
        const float4 p = *(const float4*)(img + addr);

        int v0 = min(max((int)(p.x * 255.0f), 0), 255);
        int v1 = min(max((int)(p.y * 255.0f), 0), 255);
        int v2 = min(max((int)(p.z * 255.0f), 0), 255);
        int v3 = min(max((int)(p.w * 255.0f), 0), 255);

        atomicAdd(&myh[v0], 1u);
        atomicAdd(&myh[v1], 1u);
        atomicAdd(&myh[v2], 1u);
        atomicAdd(&myh[v3], 1u);

        if (store_v) {
            uint32_t pk = (uint32_t)v0 | ((uint32_t)v1 << 8) |
                          ((uint32_t)v2 << 16) | ((uint32_t)v3 << 24);
            vpack[addr >> 2] = pk;
        }
    }
    __syncthreads();

    const uint32_t s = sh[tid] + sh[264 + tid] + sh[528 + tid] + sh[792 + tid];
    atomicAdd(&hist[(size_t)tl * 256 + tid], s);
}

// ---------------------------------------------------------------------------
// Pass 2: clip + redistribute + scan -> LUT. grid = C*64 blocks, 256 threads.
// ---------------------------------------------------------------------------
__global__ __launch_bounds__(256) void clahe_lut_kernel(
    const uint32_t* __restrict__ hist,
    float* __restrict__ lut)
{
    __shared__ uint32_t exs[4];
    __shared__ float wsum[4];

    const int tid  = threadIdx.x;
    const int wave = tid >> 6;
    const int lane = tid & 63;
    const int blk  = blockIdx.x;

    const uint32_t h  = hist[(size_t)blk * 256 + tid];
    const uint32_t cl = min(h, CLIPV);
    uint32_t ex = h - cl;

    // wave-sum of excess
#pragma unroll
    for (int d = 32; d > 0; d >>= 1) ex += __shfl_down(ex, d, 64);
    if (lane == 0) exs[wave] = ex;
    __syncthreads();
    const uint32_t extot = exs[0] + exs[1] + exs[2] + exs[3];

    float x = (float)cl + (float)extot * (1.0f / 256.0f);

    // inclusive shuffle scan within wave
#pragma unroll
    for (int d = 1; d < 64; d <<= 1) {
        float t = __shfl_up(x, d, 64);
        if (lane >= d) x += t;
    }
    if (lane == 63) wsum[wave] = x;
    __syncthreads();
    float add = 0.0f;
    for (int w = 0; w < wave; ++w) add += wsum[w];
    const float cdf = x + add;

    float l = rintf(cdf * (255.0f / (float)AREA));   // RNE == jnp.round
    l = fminf(fmaxf(l, 0.0f), 255.0f);
    lut[(size_t)blk * 256 + tid] = l;
}

// ---------------------------------------------------------------------------
// Pass 3: bilinear LUT interpolation. One thread per 4 consecutive pixels.
// grid = C*H*W/4/256 = 49152 blocks.
// ---------------------------------------------------------------------------
__global__ __launch_bounds__(256) void clahe_apply_kernel(
    const float* __restrict__ img,
    const uint32_t* __restrict__ vpack,
    const float* __restrict__ lut,
    float* __restrict__ out,
    int use_v)
{
    const int gid = blockIdx.x * 256 + threadIdx.x;   // float4 index
    const int row = gid >> 10;                        // W/4 = 1024 per row
    const int c   = row >> 12;                        // 4096 rows per channel
    const int y   = row & 4095;
    const int xp  = (gid & 1023) << 2;                // first pixel x

    const float fy = ((float)y + 0.5f) * (1.0f / (float)TH) - 0.5f;
    int y0 = (int)floorf(fy);
    y0 = min(max(y0, 0), TILES - 1);
    const float ay = fminf(fmaxf(fy - (float)y0, 0.0f), 1.0f);
    const int y1 = min(y0 + 1, TILES - 1);

    const float* lc  = lut + (size_t)c * TILES * TILES * 256;
    const float* lr0 = lc + (size_t)y0 * TILES * 256;
    const float* lr1 = lc + (size_t)y1 * TILES * 256;

    uint32_t pv = 0;
    float4 p = make_float4(0.f, 0.f, 0.f, 0.f);
    if (use_v) pv = vpack[gid];
    else       p  = *(const float4*)(img + (size_t)gid * 4);

    float res[4];
#pragma unroll
    for (int k = 0; k < 4; ++k) {
        int v;
        if (use_v) {
            v = (int)((pv >> (8 * k)) & 255u);
        } else {
            const float pk = (k == 0) ? p.x : (k == 1) ? p.y : (k == 2) ? p.z : p.w;
            v = min(max((int)(pk * 255.0f), 0), 255);
        }
        const int xx = xp + k;
        const float fx = ((float)xx + 0.5f) * (1.0f / (float)TW) - 0.5f;
        int x0 = (int)floorf(fx);
        x0 = min(max(x0, 0), TILES - 1);
        const float ax = fminf(fmaxf(fx - (float)x0, 0.0f), 1.0f);
        const int x1 = min(x0 + 1, TILES - 1);

        const float g00 = lr0[x0 * 256 + v];
        const float g01 = lr0[x1 * 256 + v];
        const float g10 = lr1[x0 * 256 + v];
        const float g11 = lr1[x1 * 256 + v];

        const float top = g00 * (1.0f - ax) + g01 * ax;
        const float bot = g10 * (1.0f - ax) + g11 * ax;
        const float o   = top * (1.0f - ay) + bot * ay;
        res[k] = o * (1.0f / 255.0f);
    }

    float4 o4 = make_float4(res[0], res[1], res[2], res[3]);
    *(float4*)(out + (size_t)gid * 4) = o4;
}

// ---------------------------------------------------------------------------
extern "C" void kernel_launch(void* const* d_in, const int* in_sizes, int n_in,
                              void* d_out, int out_size, void* d_ws, size_t ws_size,
                              hipStream_t stream)
{
    const float* img = (const float*)d_in[0];
    float* out = (float*)d_out;

    uint8_t* ws = (uint8_t*)d_ws;
    uint32_t* hist = (uint32_t*)ws;                       // 3*64*256 u32 = 196608 B
    float*    lut  = (float*)(ws + 196608);               // 3*64*256 f32 = 196608 B
    uint32_t* vpack = (uint32_t*)(ws + 393216);           // 48 MB packed v bytes

    const size_t need_v = 393216 + (size_t)CC * HH * WW;  // ~50.7 MB
    const int use_v = (ws_size >= need_v) ? 1 : 0;

    // hist must start zeroed (ws is poisoned to 0xAA before every call)
    hipMemsetAsync(hist, 0, (size_t)CC * 64 * 256 * sizeof(uint32_t), stream);

    clahe_hist_kernel<<<CC * 64 * 8, 256, 0, stream>>>(img, vpack, use_v, hist);
    clahe_lut_kernel<<<CC * 64, 256, 0, stream>>>(hist, lut);
    clahe_apply_kernel<<<(CC * HH * WW / 4) / 256, 256, 0, stream>>>(img, vpack, lut, out, use_v);
}

// Round 2
// 382.517 us; speedup vs baseline: 1.2374x; 1.2374x over previous
//
#include <hip/hip_runtime.h>
#include <stdint.h>

#define TILES 8
#define HH 4096
#define WW 4096
#define CC 3
#define TH 512
#define TW 512
#define AREA (TH * TW)
#define CLIPV 1228u   // int(1.2 * 262144 / 256)

// ---------------------------------------------------------------------------
// Pass 1: per-tile histograms + cache quantized v bytes.
// grid = 192 tiles * 16 sub-slabs = 3072 blocks, 256 threads.
// Each block: 32 rows x 512 cols of one tile, float4 loads.
// ---------------------------------------------------------------------------
__global__ __launch_bounds__(256) void clahe_hist_kernel(
    const float* __restrict__ img,
    uint32_t* __restrict__ vpack,   // packed v bytes (4 per uint)
    int store_v,
    uint32_t* __restrict__ hist)    // [C*64][256]
{
    __shared__ uint32_t sh[4 * 264];   // 4 per-wave sub-hists
    const int tid  = threadIdx.x;
    const int wave = tid >> 6;
    uint32_t* myh  = sh + wave * 264;

    for (int i = tid; i < 4 * 264; i += 256) sh[i] = 0;
    __syncthreads();

    const int bid = blockIdx.x;
    const int sub = bid & 15;       // which 32-row slab of the tile
    const int tl  = bid >> 4;       // c*64 + ty*8 + tx
    const int tx  = tl & 7;
    const int ty  = (tl >> 3) & 7;
    const int c   = tl >> 6;

    const size_t base = ((size_t)c * HH + (size_t)(ty * TH + sub * 32)) * WW + (size_t)tx * TW;

#pragma unroll 2
    for (int it = 0; it < 16; ++it) {
        const int i  = it * 256 + tid;      // [0, 4096) float4 slots
        const int rl = i >> 7;              // 128 float4 per 512-wide row
        const int c4 = i & 127;
        const size_t addr = base + (size_t)rl * WW + (size_t)c4 * 4;  // element idx
        const float4 p = *(const float4*)(img + addr);

        int v0 = min(max((int)(p.x * 255.0f), 0), 255);
        int v1 = min(max((int)(p.y * 255.0f), 0), 255);
        int v2 = min(max((int)(p.z * 255.0f), 0), 255);
        int v3 = min(max((int)(p.w * 255.0f), 0), 255);

        atomicAdd(&myh[v0], 1u);
        atomicAdd(&myh[v1], 1u);
        atomicAdd(&myh[v2], 1u);
        atomicAdd(&myh[v3], 1u);

        if (store_v) {
            uint32_t pk = (uint32_t)v0 | ((uint32_t)v1 << 8) |
                          ((uint32_t)v2 << 16) | ((uint32_t)v3 << 24);
            vpack[addr >> 2] = pk;
        }
    }
    __syncthreads();

    const uint32_t s = sh[tid] + sh[264 + tid] + sh[528 + tid] + sh[792 + tid];
    atomicAdd(&hist[(size_t)tl * 256 + tid], s);
}

// ---------------------------------------------------------------------------
// Pass 2: clip + redistribute + scan -> LUT. grid = C*64 blocks, 256 threads.
// ---------------------------------------------------------------------------
__global__ __launch_bounds__(256) void clahe_lut_kernel(
    const uint32_t* __restrict__ hist,
    float* __restrict__ lut)
{
    __shared__ uint32_t exs[4];
    __shared__ float wsum[4];

    const int tid  = threadIdx.x;
    const int wave = tid >> 6;
    const int lane = tid & 63;
    const int blk  = blockIdx.x;

    const uint32_t h  = hist[(size_t)blk * 256 + tid];
    const uint32_t cl = min(h, CLIPV);
    uint32_t ex = h - cl;

#pragma unroll
    for (int d = 32; d > 0; d >>= 1) ex += __shfl_down(ex, d, 64);
    if (lane == 0) exs[wave] = ex;
    __syncthreads();
    const uint32_t extot = exs[0] + exs[1] + exs[2] + exs[3];

    float x = (float)cl + (float)extot * (1.0f / 256.0f);

#pragma unroll
    for (int d = 1; d < 64; d <<= 1) {
        float t = __shfl_up(x, d, 64);
        if (lane >= d) x += t;
    }
    if (lane == 63) wsum[wave] = x;
    __syncthreads();
    float add = 0.0f;
    for (int w = 0; w < wave; ++w) add += wsum[w];
    const float cdf = x + add;

    float l = rintf(cdf * (255.0f / (float)AREA));   // RNE == jnp.round
    l = fminf(fmaxf(l, 0.0f), 255.0f);
    lut[(size_t)blk * 256 + tid] = l;
}

// ---------------------------------------------------------------------------
// Pass 3: one block per image row. y-blend the two tile-row LUTs into LDS
// (8 KB), then 2 LDS gathers per pixel. grid = C*H = 12288 blocks.
// ---------------------------------------------------------------------------
__global__ __launch_bounds__(256) void clahe_apply_kernel(
    const float* __restrict__ img,
    const uint32_t* __restrict__ vpack,
    const float* __restrict__ lut,
    float* __restrict__ out,
    int use_v)
{
    __shared__ float rb[TILES * 256];   // y-blended LUT for this row: [x][v]

    const int b = blockIdx.x;
    const int y = b & (HH - 1);
    const int c = b >> 12;

    const float fy = ((float)y + 0.5f) * (1.0f / (float)TH) - 0.5f;
    int y0 = (int)floorf(fy);
    y0 = min(max(y0, 0), TILES - 1);
    const float ay = fminf(fmaxf(fy - (float)y0, 0.0f), 1.0f);
    const int y1 = min(y0 + 1, TILES - 1);

    const float* lr0 = lut + ((size_t)(c * TILES + y0) * TILES) * 256;
    const float* lr1 = lut + ((size_t)(c * TILES + y1) * TILES) * 256;

#pragma unroll
    for (int k = 0; k < 8; ++k) {
        const int i = k * 256 + threadIdx.x;
        const float a = lr0[i];
        const float d = lr1[i];
        rb[i] = a + ay * (d - a);
    }
    __syncthreads();

    const size_t rowbase = ((size_t)c * HH + (size_t)y) * (WW / 4);  // float4 units
    const float4* img4 = (const float4*)img;
    float4* out4 = (float4*)out;

#pragma unroll
    for (int s = 0; s < 4; ++s) {
        const int slot = s * 256 + threadIdx.x;       // [0,1024) float4 in row

        uint32_t pv = 0;
        float4 p = make_float4(0.f, 0.f, 0.f, 0.f);
        if (use_v) pv = vpack[rowbase + slot];
        else       p  = img4[rowbase + slot];

        // all 4 pixels of an aligned float4 share x0/x1 (boundary at x=255.5+512n)
        const int xbase = slot * 4;
        const float fx0 = ((float)xbase + 0.5f) * (1.0f / (float)TW) - 0.5f;
        int x0 = (int)floorf(fx0);
        x0 = min(max(x0, 0), TILES - 1);
        const int x1 = min(x0 + 1, TILES - 1);
        const float* r0 = rb + x0 * 256;
        const float* r1 = rb + x1 * 256;
        const float fxr = fx0 - (float)x0;

        float res[4];
#pragma unroll
        for (int k = 0; k < 4; ++k) {
            int v;
            if (use_v) {
                v = (int)((pv >> (8 * k)) & 255u);
            } else {
                const float pk = (k == 0) ? p.x : (k == 1) ? p.y : (k == 2) ? p.z : p.w;
                v = min(max((int)(pk * 255.0f), 0), 255);
            }
            const float ax = fminf(fmaxf(fxr + (float)k * (1.0f / (float)TW), 0.0f), 1.0f);
            const float g0 = r0[v];
            const float g1 = r1[v];
            res[k] = (g0 + ax * (g1 - g0)) * (1.0f / 255.0f);
        }
        out4[rowbase + slot] = make_float4(res[0], res[1], res[2], res[3]);
    }
}

// ---------------------------------------------------------------------------
extern "C" void kernel_launch(void* const* d_in, const int* in_sizes, int n_in,
                              void* d_out, int out_size, void* d_ws, size_t ws_size,
                              hipStream_t stream)
{
    const float* img = (const float*)d_in[0];
    float* out = (float*)d_out;

    uint8_t* ws = (uint8_t*)d_ws;
    uint32_t* hist = (uint32_t*)ws;                       // 3*64*256 u32 = 196608 B
    float*    lut  = (float*)(ws + 196608);               // 3*64*256 f32 = 196608 B
    uint32_t* vpack = (uint32_t*)(ws + 393216);           // 48 MB packed v bytes

    const size_t need_v = 393216 + (size_t)CC * HH * WW;  // ~50.7 MB
    const int use_v = (ws_size >= need_v) ? 1 : 0;

    hipMemsetAsync(hist, 0, (size_t)CC * 64 * 256 * sizeof(uint32_t), stream);

    clahe_hist_kernel<<<CC * 64 * 16, 256, 0, stream>>>(img, vpack, use_v, hist);
    clahe_lut_kernel<<<CC * 64, 256, 0, stream>>>(hist, lut);
    clahe_apply_kernel<<<CC * HH, 256, 0, stream>>>(img, vpack, lut, out, use_v);
}

// Round 3
// 375.621 us; speedup vs baseline: 1.2601x; 1.0184x over previous
//
#include <hip/hip_runtime.h>
#include <stdint.h>

#define TILES 8
#define HH 4096
#define WW 4096
#define CC 3
#define TH 512
#define TW 512
#define AREA (TH * TW)
#define CLIPV 1228u   // int(1.2 * 262144 / 256)

// ---------------------------------------------------------------------------
// Pass 1: per-tile histograms + cache quantized v bytes.
// grid = 192 tiles * 16 sub-slabs = 3072 blocks, 256 threads.
// Each block: 32 rows x 512 cols of one tile. 4 independent float4 loads
// per iteration for memory-level parallelism.
// ---------------------------------------------------------------------------
__global__ __launch_bounds__(256) void clahe_hist_kernel(
    const float* __restrict__ img,
    uint32_t* __restrict__ vpack,   // packed v bytes (4 per uint)
    int store_v,
    uint32_t* __restrict__ hist)    // [C*64][256]
{
    __shared__ uint32_t sh[4 * 264];   // 4 per-wave sub-hists
    const int tid  = threadIdx.x;
    const int wave = tid >> 6;
    uint32_t* myh  = sh + wave * 264;

    for (int i = tid; i < 4 * 264; i += 256) sh[i] = 0;
    __syncthreads();

    const int bid = blockIdx.x;
    const int sub = bid & 15;       // which 32-row slab of the tile
    const int tl  = bid >> 4;       // c*64 + ty*8 + tx
    const int tx  = tl & 7;
    const int ty  = (tl >> 3) & 7;
    const int c   = tl >> 6;

    const size_t base = ((size_t)c * HH + (size_t)(ty * TH + sub * 32)) * WW + (size_t)tx * TW;

    for (int it = 0; it < 4; ++it) {
        const int i0 = it * 1024 + tid;
        size_t addr[4];
        float4 p[4];
#pragma unroll
        for (int j = 0; j < 4; ++j) {
            const int s  = i0 + j * 256;       // [0,4096) float4 slot
            const int rl = s >> 7;             // 128 float4 per 512-wide row
            const int c4 = s & 127;
            addr[j] = base + (size_t)rl * WW + (size_t)c4 * 4;
            p[j] = *(const float4*)(img + addr[j]);   // 4 independent loads in flight
        }
#pragma unroll
        for (int j = 0; j < 4; ++j) {
            int v0 = min(max((int)(p[j].x * 255.0f), 0), 255);
            int v1 = min(max((int)(p[j].y * 255.0f), 0), 255);
            int v2 = min(max((int)(p[j].z * 255.0f), 0), 255);
            int v3 = min(max((int)(p[j].w * 255.0f), 0), 255);

            atomicAdd(&myh[v0], 1u);
            atomicAdd(&myh[v1], 1u);
            atomicAdd(&myh[v2], 1u);
            atomicAdd(&myh[v3], 1u);

            if (store_v) {
                uint32_t pk = (uint32_t)v0 | ((uint32_t)v1 << 8) |
                              ((uint32_t)v2 << 16) | ((uint32_t)v3 << 24);
                vpack[addr[j] >> 2] = pk;
            }
        }
    }
    __syncthreads();

    const uint32_t s = sh[tid] + sh[264 + tid] + sh[528 + tid] + sh[792 + tid];
    atomicAdd(&hist[(size_t)tl * 256 + tid], s);
}

// ---------------------------------------------------------------------------
// Pass 2: clip + redistribute + scan -> LUT. grid = C*64 blocks, 256 threads.
// ---------------------------------------------------------------------------
__global__ __launch_bounds__(256) void clahe_lut_kernel(
    const uint32_t* __restrict__ hist,
    float* __restrict__ lut)
{
    __shared__ uint32_t exs[4];
    __shared__ float wsum[4];

    const int tid  = threadIdx.x;
    const int wave = tid >> 6;
    const int lane = tid & 63;
    const int blk  = blockIdx.x;

    const uint32_t h  = hist[(size_t)blk * 256 + tid];
    const uint32_t cl = min(h, CLIPV);
    uint32_t ex = h - cl;

#pragma unroll
    for (int d = 32; d > 0; d >>= 1) ex += __shfl_down(ex, d, 64);
    if (lane == 0) exs[wave] = ex;
    __syncthreads();
    const uint32_t extot = exs[0] + exs[1] + exs[2] + exs[3];

    float x = (float)cl + (float)extot * (1.0f / 256.0f);

#pragma unroll
    for (int d = 1; d < 64; d <<= 1) {
        float t = __shfl_up(x, d, 64);
        if (lane >= d) x += t;
    }
    if (lane == 63) wsum[wave] = x;
    __syncthreads();
    float add = 0.0f;
    for (int w = 0; w < wave; ++w) add += wsum[w];
    const float cdf = x + add;

    float l = rintf(cdf * (255.0f / (float)AREA));   // RNE == jnp.round
    l = fminf(fmaxf(l, 0.0f), 255.0f);
    lut[(size_t)blk * 256 + tid] = l;
}

// ---------------------------------------------------------------------------
// Pass 3: 8 rows per block (aligned 8-row groups share y0/y1 — band
// boundaries are multiples of 256). Cache lr0/lr1 in registers once; per row
// blend into LDS rb, then 2 LDS gathers per pixel. grid = C*512 blocks.
// ---------------------------------------------------------------------------
__global__ __launch_bounds__(256) void clahe_apply_kernel(
    const float* __restrict__ img,
    const uint32_t* __restrict__ vpack,
    const float* __restrict__ lut,
    float* __restrict__ out,
    int use_v)
{
    __shared__ float rb[TILES * 256];   // y-blended LUT for current row: [x][v]

    const int b = blockIdx.x;
    const int g = b & 511;              // 8-row group within channel
    const int c = b >> 9;
    const int ybase = g * 8;
    const int tid = threadIdx.x;

    // y0/y1 uniform across the 8-row group
    const float fyb = ((float)ybase + 0.5f) * (1.0f / (float)TH) - 0.5f;
    int y0 = (int)floorf(fyb);
    y0 = min(max(y0, 0), TILES - 1);
    const int y1 = min(y0 + 1, TILES - 1);

    const float* lr0 = lut + ((size_t)(c * TILES + y0) * TILES) * 256;
    const float* lr1 = lut + ((size_t)(c * TILES + y1) * TILES) * 256;

    float a0[8], a1[8];
#pragma unroll
    for (int k = 0; k < 8; ++k) {
        a0[k] = lr0[k * 256 + tid];
        a1[k] = lr1[k * 256 + tid];
    }

    const float4* img4 = (const float4*)img;
    float4* out4 = (float4*)out;

    for (int r = 0; r < 8; ++r) {
        const int y = ybase + r;
        const float fy = ((float)y + 0.5f) * (1.0f / (float)TH) - 0.5f;
        const float ay = fminf(fmaxf(fy - (float)y0, 0.0f), 1.0f);

        if (r) __syncthreads();          // previous row's gathers done
#pragma unroll
        for (int k = 0; k < 8; ++k)
            rb[k * 256 + tid] = a0[k] + ay * (a1[k] - a0[k]);
        __syncthreads();

        const size_t rowbase = ((size_t)c * HH + (size_t)y) * (WW / 4);

#pragma unroll
        for (int s = 0; s < 4; ++s) {
            const int slot = s * 256 + tid;      // [0,1024) float4 in row

            uint32_t pv = 0;
            float4 p = make_float4(0.f, 0.f, 0.f, 0.f);
            if (use_v) pv = vpack[rowbase + slot];
            else       p  = img4[rowbase + slot];

            // all 4 pixels of an aligned float4 share x0/x1
            const int xbase = slot * 4;
            const float fx0 = ((float)xbase + 0.5f) * (1.0f / (float)TW) - 0.5f;
            int x0 = (int)floorf(fx0);
            x0 = min(max(x0, 0), TILES - 1);
            const int x1 = min(x0 + 1, TILES - 1);
            const float* r0 = rb + x0 * 256;
            const float* r1 = rb + x1 * 256;
            const float fxr = fx0 - (float)x0;

            float res[4];
#pragma unroll
            for (int k = 0; k < 4; ++k) {
                int v;
                if (use_v) {
                    v = (int)((pv >> (8 * k)) & 255u);
                } else {
                    const float pk = (k == 0) ? p.x : (k == 1) ? p.y : (k == 2) ? p.z : p.w;
                    v = min(max((int)(pk * 255.0f), 0), 255);
                }
                const float ax = fminf(fmaxf(fxr + (float)k * (1.0f / (float)TW), 0.0f), 1.0f);
                const float g0 = r0[v];
                const float g1 = r1[v];
                res[k] = (g0 + ax * (g1 - g0)) * (1.0f / 255.0f);
            }
            out4[rowbase + slot] = make_float4(res[0], res[1], res[2], res[3]);
        }
    }
}

// ---------------------------------------------------------------------------
extern "C" void kernel_launch(void* const* d_in, const int* in_sizes, int n_in,
                              void* d_out, int out_size, void* d_ws, size_t ws_size,
                              hipStream_t stream)
{
    const float* img = (const float*)d_in[0];
    float* out = (float*)d_out;

    uint8_t* ws = (uint8_t*)d_ws;
    uint32_t* hist = (uint32_t*)ws;                       // 3*64*256 u32 = 196608 B
    float*    lut  = (float*)(ws + 196608);               // 3*64*256 f32 = 196608 B
    uint32_t* vpack = (uint32_t*)(ws + 393216);           // 48 MB packed v bytes

    const size_t need_v = 393216 + (size_t)CC * HH * WW;  // ~50.7 MB
    const int use_v = (ws_size >= need_v) ? 1 : 0;

    hipMemsetAsync(hist, 0, (size_t)CC * 64 * 256 * sizeof(uint32_t), stream);

    clahe_hist_kernel<<<CC * 64 * 16, 256, 0, stream>>>(img, vpack, use_v, hist);
    clahe_lut_kernel<<<CC * 64, 256, 0, stream>>>(hist, lut);
    clahe_apply_kernel<<<CC * 512, 256, 0, stream>>>(img, vpack, lut, out, use_v);
}

// Round 4
// 335.791 us; speedup vs baseline: 1.4095x; 1.1186x over previous
//
#include <hip/hip_runtime.h>
#include <stdint.h>

#define TILES 8
#define HH 4096
#define WW 4096
#define CC 3
#define TH 512
#define TW 512
#define AREA (TH * TW)
#define CLIPV 1228u   // int(1.2 * 262144 / 256)

typedef float f4 __attribute__((ext_vector_type(4)));

// ---------------------------------------------------------------------------
// Pass 1: per-tile partial histograms + cache quantized v bytes.
// grid = 192 tiles * 16 sub-slabs = 3072 blocks, 256 threads.
// Each block: 32 rows x 512 cols of one tile. Nontemporal img loads (no
// reuse). Each block writes its own hist_part[bid][256] -- no global atomics,
// no zero-init needed.
// ---------------------------------------------------------------------------
__global__ __launch_bounds__(256) void clahe_hist_kernel(
    const float* __restrict__ img,
    uint32_t* __restrict__ vpack,        // packed v bytes (4 per uint)
    int store_v,
    uint32_t* __restrict__ hist_part)    // [3072][256]
{
    __shared__ uint32_t sh[4 * 264];   // 4 per-wave sub-hists
    const int tid  = threadIdx.x;
    const int wave = tid >> 6;
    uint32_t* myh  = sh + wave * 264;

    for (int i = tid; i < 4 * 264; i += 256) sh[i] = 0;
    __syncthreads();

    const int bid = blockIdx.x;
    const int sub = bid & 15;       // which 32-row slab of the tile
    const int tl  = bid >> 4;       // c*64 + ty*8 + tx
    const int tx  = tl & 7;
    const int ty  = (tl >> 3) & 7;
    const int c   = tl >> 6;

    // base in float4 units
    const size_t base4 = ((size_t)c * HH + (size_t)(ty * TH + sub * 32)) * (WW / 4)
                       + (size_t)tx * (TW / 4);
    const f4* img4 = (const f4*)img;

    for (int it = 0; it < 4; ++it) {
        const int i0 = it * 1024 + tid;
        size_t addr[4];
        f4 p[4];
#pragma unroll
        for (int j = 0; j < 4; ++j) {
            const int s  = i0 + j * 256;       // [0,4096) float4 slot
            const int rl = s >> 7;             // 128 float4 per 512-wide row
            const int c4 = s & 127;
            addr[j] = base4 + (size_t)rl * (WW / 4) + (size_t)c4;
            p[j] = __builtin_nontemporal_load(&img4[addr[j]]);  // 4 loads in flight
        }
#pragma unroll
        for (int j = 0; j < 4; ++j) {
            int v0 = min(max((int)(p[j][0] * 255.0f), 0), 255);
            int v1 = min(max((int)(p[j][1] * 255.0f), 0), 255);
            int v2 = min(max((int)(p[j][2] * 255.0f), 0), 255);
            int v3 = min(max((int)(p[j][3] * 255.0f), 0), 255);

            atomicAdd(&myh[v0], 1u);
            atomicAdd(&myh[v1], 1u);
            atomicAdd(&myh[v2], 1u);
            atomicAdd(&myh[v3], 1u);

            if (store_v) {
                uint32_t pk = (uint32_t)v0 | ((uint32_t)v1 << 8) |
                              ((uint32_t)v2 << 16) | ((uint32_t)v3 << 24);
                vpack[addr[j]] = pk;           // normal store: want LLC residency
            }
        }
    }
    __syncthreads();

    const uint32_t s = sh[tid] + sh[264 + tid] + sh[528 + tid] + sh[792 + tid];
    hist_part[(size_t)bid * 256 + tid] = s;    // plain coalesced store
}

// ---------------------------------------------------------------------------
// Pass 2: sum 16 partials, clip + redistribute + scan -> LUT.
// grid = C*64 blocks, 256 threads.
// ---------------------------------------------------------------------------
__global__ __launch_bounds__(256) void clahe_lut_kernel(
    const uint32_t* __restrict__ hist_part,
    float* __restrict__ lut)
{
    __shared__ uint32_t exs[4];
    __shared__ float wsum[4];

    const int tid  = threadIdx.x;
    const int wave = tid >> 6;
    const int lane = tid & 63;
    const int blk  = blockIdx.x;

    const uint32_t* hp = hist_part + (size_t)blk * 16 * 256;
    uint32_t h = 0;
#pragma unroll
    for (int s = 0; s < 16; ++s) h += hp[s * 256 + tid];

    const uint32_t cl = min(h, CLIPV);
    uint32_t ex = h - cl;

#pragma unroll
    for (int d = 32; d > 0; d >>= 1) ex += __shfl_down(ex, d, 64);
    if (lane == 0) exs[wave] = ex;
    __syncthreads();
    const uint32_t extot = exs[0] + exs[1] + exs[2] + exs[3];

    float x = (float)cl + (float)extot * (1.0f / 256.0f);

#pragma unroll
    for (int d = 1; d < 64; d <<= 1) {
        float t = __shfl_up(x, d, 64);
        if (lane >= d) x += t;
    }
    if (lane == 63) wsum[wave] = x;
    __syncthreads();
    float add = 0.0f;
    for (int w = 0; w < wave; ++w) add += wsum[w];
    const float cdf = x + add;

    float l = rintf(cdf * (255.0f / (float)AREA));   // RNE == jnp.round
    l = fminf(fmaxf(l, 0.0f), 255.0f);
    lut[(size_t)blk * 256 + tid] = l;
}

// ---------------------------------------------------------------------------
// Pass 3: one block per image row. Prefetch the row's pixel data FIRST (loads
// stay in flight across the barrier), y-blend the two tile-row LUTs into LDS,
// then 2 LDS gathers per pixel. Single barrier; out stores at block end via
// nontemporal (out is never re-read). grid = C*H = 12288 blocks.
// ---------------------------------------------------------------------------
__global__ __launch_bounds__(256) void clahe_apply_kernel(
    const float* __restrict__ img,
    const uint32_t* __restrict__ vpack,
    const float* __restrict__ lut,
    float* __restrict__ out,
    int use_v)
{
    __shared__ float rb[TILES * 256];   // y-blended LUT for this row: [x][v]

    const int tid = threadIdx.x;
    const int b = blockIdx.x;
    const int y = b & (HH - 1);
    const int c = b >> 12;

    const size_t rowbase4 = ((size_t)c * HH + (size_t)y) * (WW / 4);
    const f4* img4 = (const f4*)img;

    // ---- prefetch pixel data for all 4 slots (in flight during rb fill) ----
    uint32_t pv[4];
    f4 p[4];
    if (use_v) {
#pragma unroll
        for (int s = 0; s < 4; ++s) pv[s] = vpack[rowbase4 + s * 256 + tid];
    } else {
#pragma unroll
        for (int s = 0; s < 4; ++s) p[s] = img4[rowbase4 + s * 256 + tid];
    }

    // ---- rb fill ----
    const float fy = ((float)y + 0.5f) * (1.0f / (float)TH) - 0.5f;
    int y0 = (int)floorf(fy);
    y0 = min(max(y0, 0), TILES - 1);
    const float ay = fminf(fmaxf(fy - (float)y0, 0.0f), 1.0f);
    const int y1 = min(y0 + 1, TILES - 1);

    const float* lr0 = lut + ((size_t)(c * TILES + y0) * TILES) * 256;
    const float* lr1 = lut + ((size_t)(c * TILES + y1) * TILES) * 256;

#pragma unroll
    for (int k = 0; k < 8; ++k) {
        const int i = k * 256 + tid;
        const float a = lr0[i];
        const float d = lr1[i];
        rb[i] = a + ay * (d - a);
    }
    __syncthreads();

#pragma unroll
    for (int s = 0; s < 4; ++s) {
        const int slot = s * 256 + tid;       // [0,1024) float4 in row

        // all 4 pixels of an aligned float4 share x0/x1 (boundary at 255.5+512n)
        const int xbase = slot * 4;
        const float fx0 = ((float)xbase + 0.5f) * (1.0f / (float)TW) - 0.5f;
        int x0 = (int)floorf(fx0);
        x0 = min(max(x0, 0), TILES - 1);
        const int x1 = min(x0 + 1, TILES - 1);
        const float* r0 = rb + x0 * 256;
        const float* r1 = rb + x1 * 256;
        const float fxr = fx0 - (float)x0;

        float res[4];
#pragma unroll
        for (int k = 0; k < 4; ++k) {
            int v;
            if (use_v) {
                v = (int)((pv[s] >> (8 * k)) & 255u);
            } else {
                v = min(max((int)(p[s][k] * 255.0f), 0), 255);
            }
            const float ax = fminf(fmaxf(fxr + (float)k * (1.0f / (float)TW), 0.0f), 1.0f);
            const float g0 = r0[v];
            const float g1 = r1[v];
            res[k] = (g0 + ax * (g1 - g0)) * (1.0f / 255.0f);
        }
        f4 o4 = { res[0], res[1], res[2], res[3] };
        __builtin_nontemporal_store(o4, ((f4*)out) + rowbase4 + slot);
    }
}

// ---------------------------------------------------------------------------
extern "C" void kernel_launch(void* const* d_in, const int* in_sizes, int n_in,
                              void* d_out, int out_size, void* d_ws, size_t ws_size,
                              hipStream_t stream)
{
    const float* img = (const float*)d_in[0];
    float* out = (float*)d_out;

    uint8_t* ws = (uint8_t*)d_ws;
    float*    lut       = (float*)ws;                     // 3*64*256 f32 = 196608 B
    uint32_t* hist_part = (uint32_t*)(ws + 196608);       // 3072*256 u32 = 3145728 B
    uint32_t* vpack     = (uint32_t*)(ws + 196608 + 3145728);  // 48 MB packed v

    const size_t need_v = 196608 + 3145728 + (size_t)CC * HH * WW;
    const int use_v = (ws_size >= need_v) ? 1 : 0;

    clahe_hist_kernel<<<CC * 64 * 16, 256, 0, stream>>>(img, vpack, use_v, hist_part);
    clahe_lut_kernel<<<CC * 64, 256, 0, stream>>>(hist_part, lut);
    clahe_apply_kernel<<<CC * HH, 256, 0, stream>>>(img, vpack, lut, out, use_v);
}